// Round 1
// baseline (748.589 us; speedup 1.0000x reference)
//
#include <hip/hip_runtime.h>
#include <cstdint>
#include <cstddef>

#define B_DIM 4
#define C_DIM 512
#define T_DIM 1024
#define D_DIM 128
#define L_DIM 101
#define O_DIM 128

// ---------------- K1: spatial mean pool ----------------
// x[b][c][t][8][8] -> feat[b*1024+t][c], feat = mean over the 64 spatial elems.
// 16 lanes per (b,c,t) group, each reads one float4 of the contiguous 64 floats.
__global__ __launch_bounds__(256) void pool_kernel(const float* __restrict__ x,
                                                   float* __restrict__ feat) {
    const int bt  = blockIdx.x;           // b*1024 + t
    const int b   = bt >> 10;
    const int t   = bt & (T_DIM - 1);
    const int tid = threadIdx.x;
    const int sub = tid & 15;             // which float4 of the 64-elem group
    const int gi  = tid >> 4;             // 0..15  (c sub-index)
    __shared__ float feat_s[C_DIM];

    #pragma unroll 4
    for (int it = 0; it < C_DIM / 16; ++it) {
        const int c = it * 16 + gi;
        const size_t gidx = ((((size_t)b * C_DIM + c) * T_DIM + t) << 6) + (sub << 2);
        const float4 v = *(const float4*)(x + gidx);
        float s = v.x + v.y + v.z + v.w;
        s += __shfl_down(s, 8, 16);
        s += __shfl_down(s, 4, 16);
        s += __shfl_down(s, 2, 16);
        s += __shfl_down(s, 1, 16);
        if (sub == 0) feat_s[c] = s * (1.0f / 64.0f);
    }
    __syncthreads();
    if (tid < C_DIM / 4) {  // coalesced 2 KiB row write
        ((float4*)(feat + (size_t)bt * C_DIM))[tid] = ((const float4*)feat_s)[tid];
    }
}

// ---------------- K2: projection GEMM + L2 normalize ----------------
// p[row][d] = sum_c feat[row][c] * Wp[d][c], then row-normalized.
#define K2_ROWS 16
#define K2_KT 64
#define BS_STRIDE 132   // pad: store conflicts 16-way -> 8-way; 132*4B = 16B-aligned rows

__global__ __launch_bounds__(256) void proj_norm_kernel(const float* __restrict__ feat,
                                                        const float* __restrict__ Wp,
                                                        float* __restrict__ p) {
    __shared__ float As[K2_ROWS * K2_KT];     // [row][k] stride 64
    __shared__ float Bs[K2_KT * BS_STRIDE];   // [k][d]   stride 132
    const int tid  = threadIdx.x;
    const int row0 = blockIdx.x * K2_ROWS;
    const int tr   = tid >> 5;   // 0..7 -> row pair
    const int tc   = tid & 31;   // 0..31 -> col quad
    const int r0   = tr * 2;
    const int c0   = tc * 4;

    float acc0[4] = {0.f, 0.f, 0.f, 0.f};
    float acc1[4] = {0.f, 0.f, 0.f, 0.f};

    for (int kt = 0; kt < C_DIM / K2_KT; ++kt) {
        const int k0 = kt * K2_KT;
        {   // stage A tile: 16 rows x 64 k (coalesced float4)
            const int i  = tid >> 4;
            const int k4 = (tid & 15) << 2;
            *(float4*)(As + i * K2_KT + k4) =
                *(const float4*)(feat + (size_t)(row0 + i) * C_DIM + k0 + k4);
        }
        #pragma unroll
        for (int j = 0; j < 8; ++j) {   // stage B tile transposed: Bs[k][d]
            const int idx = tid + (j << 8);
            const int d   = idx >> 4;
            const int kk  = (idx & 15) << 2;
            const float4 v = *(const float4*)(Wp + (size_t)d * C_DIM + k0 + kk);
            Bs[(kk + 0) * BS_STRIDE + d] = v.x;
            Bs[(kk + 1) * BS_STRIDE + d] = v.y;
            Bs[(kk + 2) * BS_STRIDE + d] = v.z;
            Bs[(kk + 3) * BS_STRIDE + d] = v.w;
        }
        __syncthreads();
        #pragma unroll 8
        for (int k = 0; k < K2_KT; ++k) {
            const float a0 = As[(r0 + 0) * K2_KT + k];   // 2 addrs/wave: broadcast
            const float a1 = As[(r0 + 1) * K2_KT + k];
            const float4 b4 = *(const float4*)(Bs + k * BS_STRIDE + c0); // conflict-free
            acc0[0] += a0 * b4.x; acc0[1] += a0 * b4.y;
            acc0[2] += a0 * b4.z; acc0[3] += a0 * b4.w;
            acc1[0] += a1 * b4.x; acc1[1] += a1 * b4.y;
            acc1[2] += a1 * b4.z; acc1[3] += a1 * b4.w;
        }
        __syncthreads();
    }

    // rows live entirely within one 32-lane group -> shfl-xor reduce sumsq
    float ss0 = acc0[0]*acc0[0] + acc0[1]*acc0[1] + acc0[2]*acc0[2] + acc0[3]*acc0[3];
    float ss1 = acc1[0]*acc1[0] + acc1[1]*acc1[1] + acc1[2]*acc1[2] + acc1[3]*acc1[3];
    #pragma unroll
    for (int off = 16; off >= 1; off >>= 1) {
        ss0 += __shfl_xor(ss0, off, 32);
        ss1 += __shfl_xor(ss1, off, 32);
    }
    const float inv0 = 1.0f / fmaxf(sqrtf(ss0), 1e-12f);
    const float inv1 = 1.0f / fmaxf(sqrtf(ss1), 1e-12f);
    const float4 o0 = make_float4(acc0[0]*inv0, acc0[1]*inv0, acc0[2]*inv0, acc0[3]*inv0);
    const float4 o1 = make_float4(acc1[0]*inv1, acc1[1]*inv1, acc1[2]*inv1, acc1[3]*inv1);
    *(float4*)(p + (size_t)(row0 + r0 + 0) * D_DIM + c0) = o0;
    *(float4*)(p + (size_t)(row0 + r0 + 1) * D_DIM + c0) = o1;
}

// ---------------- K3a: banded similarity ----------------
// band[bt][l] = dot(p[bt], p[b, t+l-50]) with zero padding outside [0,T).
#define TT 16
#define P_STRIDE 129               // conflict-free row-major dot reads
#define NROWS (TT + 100)           // 116

__global__ __launch_bounds__(256) void band_kernel(const float* __restrict__ p,
                                                   float* __restrict__ band) {
    __shared__ float p_s[NROWS * P_STRIDE];   // 59856 B
    const int tid = threadIdx.x;
    const int b   = blockIdx.x >> 6;
    const int t0  = (blockIdx.x & 63) * TT;

    for (int idx = tid; idx < NROWS * (D_DIM / 4); idx += 256) {
        const int i  = idx >> 5;
        const int k4 = (idx & 31) << 2;
        const int r  = t0 - 50 + i;
        float4 v = make_float4(0.f, 0.f, 0.f, 0.f);
        if (r >= 0 && r < T_DIM)
            v = *(const float4*)(p + (size_t)((b << 10) + r) * D_DIM + k4);
        float* dst = p_s + i * P_STRIDE + k4;  // scalar stores (odd stride)
        dst[0] = v.x; dst[1] = v.y; dst[2] = v.z; dst[3] = v.w;
    }
    __syncthreads();

    const size_t base = (size_t)((b << 10) + t0) * L_DIM;
    for (int idx = tid; idx < TT * L_DIM; idx += 256) {
        const int t = idx / L_DIM;
        const int l = idx - t * L_DIM;
        const float* pa = p_s + (t + 50) * P_STRIDE;  // local row of global t0+t
        const float* pb = p_s + (t + l) * P_STRIDE;   // local row of global t0+t+l-50
        float s = 0.f;
        #pragma unroll 8
        for (int k = 0; k < D_DIM; ++k) s += pa[k] * pb[k];
        band[base + idx] = s;   // OOB rows were zero-filled -> dot is exactly 0
    }
}

// ---------------- K3b: band @ W_fc^T + bias, relu ----------------
__global__ __launch_bounds__(256) void fc_kernel(const float* __restrict__ band,
                                                 const float* __restrict__ Wfc,
                                                 const float* __restrict__ bfc,
                                                 float* __restrict__ out) {
    __shared__ float wfc_s[O_DIM * L_DIM];   // 51712 B
    __shared__ float band_s[TT * L_DIM];     // 6464 B
    const int tid = threadIdx.x;
    const int b   = blockIdx.x >> 6;
    const int t0  = (blockIdx.x & 63) * TT;
    const size_t base = (size_t)((b << 10) + t0) * L_DIM;

    for (int idx = tid; idx < O_DIM * L_DIM; idx += 256) wfc_s[idx] = Wfc[idx];
    for (int idx = tid; idx < TT * L_DIM; idx += 256)    band_s[idx] = band[base + idx];
    __syncthreads();

    const int o  = tid & 127;
    const int th = tid >> 7;   // 0..1
    const float bias = bfc[o];
    const float* w = wfc_s + o * L_DIM;  // (5o+l)%32 -> 2-way across 64 lanes: free
    #pragma unroll
    for (int pass = 0; pass < TT / 2; ++pass) {
        const int t = pass * 2 + th;
        const float* bd = band_s + t * L_DIM;  // broadcast across o-lanes
        float acc = bias;
        for (int l = 0; l < L_DIM; ++l) acc += bd[l] * w[l];
        out[(size_t)((b << 10) + t0 + t) * O_DIM + o] = fmaxf(acc, 0.f);
    }
}

extern "C" void kernel_launch(void* const* d_in, const int* in_sizes, int n_in,
                              void* d_out, int out_size, void* d_ws, size_t ws_size,
                              hipStream_t stream) {
    const float* x   = (const float*)d_in[0];
    const float* Wp  = (const float*)d_in[1];
    const float* Wfc = (const float*)d_in[2];
    const float* bfc = (const float*)d_in[3];
    float* out = (float*)d_out;

    char* ws = (char*)d_ws;
    float* feat = (float*)(ws);                              // 8 MiB
    float* p    = (float*)(ws + (size_t)8  * 1024 * 1024);   // 2 MiB
    float* band = (float*)(ws + (size_t)10 * 1024 * 1024);   // ~1.58 MiB

    pool_kernel<<<B_DIM * T_DIM, 256, 0, stream>>>(x, feat);
    proj_norm_kernel<<<(B_DIM * T_DIM) / K2_ROWS, 256, 0, stream>>>(feat, Wp, p);
    band_kernel<<<B_DIM * (T_DIM / TT), 256, 0, stream>>>(p, band);
    fc_kernel<<<B_DIM * (T_DIM / TT), 256, 0, stream>>>(band, Wfc, bfc, out);
}

// Round 2
// 715.863 us; speedup vs baseline: 1.0457x; 1.0457x over previous
//
#include <hip/hip_runtime.h>
#include <cstdint>
#include <cstddef>

#define B_DIM 4
#define C_DIM 512
#define T_DIM 1024
#define D_DIM 128
#define L_DIM 101
#define O_DIM 128

// ---------------- K0: transpose W_proj (128x512) -> WpT (512x128) ----------------
__global__ __launch_bounds__(256) void wpt_kernel(const float* __restrict__ Wp,
                                                  float* __restrict__ WpT) {
    const int idx = blockIdx.x * 256 + threadIdx.x;   // 65536 total
    const int c = idx >> 7;
    const int d = idx & 127;
    WpT[idx] = Wp[d * C_DIM + c];   // write coalesced, read scattered (L2)
}

// ---------------- K1: fused pool + proj + L2-normalize ----------------
// 4 (b,t) rows per block; 1024 blocks.
#define ROWS 4
__global__ __launch_bounds__(256) void pool_proj_kernel(const float* __restrict__ x,
                                                        const float* __restrict__ WpT,
                                                        float* __restrict__ p) {
    __shared__ float feat_s[ROWS * C_DIM];          // 8 KB  [row][c]
    __shared__ float red_s[8 * ROWS * D_DIM];       // 16 KB [strm][row][d]
    __shared__ float nrm_s[ROWS * 2];
    const int tid = threadIdx.x;
    const int bt0 = blockIdx.x * ROWS;
    const int b   = bt0 >> 10;
    const int t0  = bt0 & (T_DIM - 1);

    // ---- phase A: spatial mean pool into feat_s ----
    {
        const int sub = tid & 15;   // float4 slot within the 64-float group
        const int grp = tid >> 4;   // 0..15
        #pragma unroll 4
        for (int it = 0; it < (ROWS * C_DIM) / 16; ++it) {   // 128 iters
            const int idx = it * 16 + grp;                    // row*512 + c
            const int row = idx >> 9;
            const int c   = idx & (C_DIM - 1);
            const size_t gidx =
                ((((size_t)b * C_DIM + c) * T_DIM + (t0 + row)) << 6) + (sub << 2);
            const float4 v = *(const float4*)(x + gidx);
            float s = v.x + v.y + v.z + v.w;
            s += __shfl_down(s, 8, 16);
            s += __shfl_down(s, 4, 16);
            s += __shfl_down(s, 2, 16);
            s += __shfl_down(s, 1, 16);
            if (sub == 0) feat_s[idx] = s * (1.0f / 64.0f);
        }
    }
    __syncthreads();

    // ---- phase B: proj.  lane owns d-quad, strm owns c = 8k+strm ----
    {
        const int lane4 = (tid & 31) << 2;   // d0
        const int strm  = tid >> 5;          // 0..7
        float a0[4] = {0,0,0,0}, a1[4] = {0,0,0,0}, a2[4] = {0,0,0,0}, a3[4] = {0,0,0,0};
        for (int ci = 0; ci < C_DIM / 8; ++ci) {
            const int c = ci * 8 + strm;
            const float4 w = *(const float4*)(WpT + (size_t)c * D_DIM + lane4);
            const float f0 = feat_s[0 * C_DIM + c];
            const float f1 = feat_s[1 * C_DIM + c];
            const float f2 = feat_s[2 * C_DIM + c];
            const float f3 = feat_s[3 * C_DIM + c];
            a0[0] += f0 * w.x; a0[1] += f0 * w.y; a0[2] += f0 * w.z; a0[3] += f0 * w.w;
            a1[0] += f1 * w.x; a1[1] += f1 * w.y; a1[2] += f1 * w.z; a1[3] += f1 * w.w;
            a2[0] += f2 * w.x; a2[1] += f2 * w.y; a2[2] += f2 * w.z; a2[3] += f2 * w.w;
            a3[0] += f3 * w.x; a3[1] += f3 * w.y; a3[2] += f3 * w.z; a3[3] += f3 * w.w;
        }
        float* rb = red_s + strm * (ROWS * D_DIM) + lane4;
        *(float4*)(rb + 0 * D_DIM) = make_float4(a0[0], a0[1], a0[2], a0[3]);
        *(float4*)(rb + 1 * D_DIM) = make_float4(a1[0], a1[1], a1[2], a1[3]);
        *(float4*)(rb + 2 * D_DIM) = make_float4(a2[0], a2[1], a2[2], a2[3]);
        *(float4*)(rb + 3 * D_DIM) = make_float4(a3[0], a3[1], a3[2], a3[3]);
    }
    __syncthreads();

    // ---- phase C: combine streams + row-norm + store ----
    float pv[2];
    const int lane = tid & 63;
    const int wv   = tid >> 6;
    #pragma unroll
    for (int j = 0; j < 2; ++j) {
        const int idx = j * 256 + tid;       // row*128 + d
        const int rd  = idx;                 // red_s row*128+d offset
        float v = 0.f;
        #pragma unroll
        for (int s = 0; s < 8; ++s) v += red_s[s * (ROWS * D_DIM) + rd];
        pv[j] = v;
        float ss = v * v;
        ss += __shfl_xor(ss, 32, 64);
        ss += __shfl_xor(ss, 16, 64);
        ss += __shfl_xor(ss,  8, 64);
        ss += __shfl_xor(ss,  4, 64);
        ss += __shfl_xor(ss,  2, 64);
        ss += __shfl_xor(ss,  1, 64);
        if (lane == 0) {
            const int row  = (j * 4 + wv) >> 1;
            const int half = wv & 1;
            nrm_s[row * 2 + half] = ss;
        }
    }
    __syncthreads();
    #pragma unroll
    for (int j = 0; j < 2; ++j) {
        const int idx = j * 256 + tid;
        const int row = idx >> 7;
        const int d   = idx & 127;
        const float ss  = nrm_s[row * 2] + nrm_s[row * 2 + 1];
        const float inv = 1.0f / fmaxf(sqrtf(ss), 1e-12f);
        p[(size_t)(bt0 + row) * D_DIM + d] = pv[j] * inv;
    }
}

// ---------------- K2: fused banded similarity + FC + relu ----------------
// 8 t's per block; 512 blocks; 2 blocks/CU.
#define TT 8
#define PS 129                 // odd-ish stride -> conflict-free row reads
#define NR 109                 // 8 + 100 halo + 1 pad row for the l-pair tail
#define SMEM_F (NR * PS)       // 14061 floats = 56244 B

__global__ __launch_bounds__(256) void band_fc_kernel(const float* __restrict__ p,
                                                      const float* __restrict__ Wfc,
                                                      const float* __restrict__ bfc,
                                                      float* __restrict__ out) {
    __shared__ float smem[SMEM_F];
    float* p_s = smem;                                  // [NR][PS]
    const int tid = threadIdx.x;
    const int b   = blockIdx.x >> 7;
    const int t0  = (blockIdx.x & 127) * TT;

    // ---- load p rows t0-50 .. t0+58 (zero-filled OOB) ----
    for (int idx = tid; idx < NR * (D_DIM / 4); idx += 256) {
        const int i  = idx >> 5;
        const int k4 = (idx & 31) << 2;
        const int r  = t0 - 50 + i;
        float4 v = make_float4(0.f, 0.f, 0.f, 0.f);
        if (r >= 0 && r < T_DIM)
            v = *(const float4*)(p + (size_t)((b << 10) + r) * D_DIM + k4);
        float* dst = p_s + i * PS + k4;
        dst[0] = v.x; dst[1] = v.y; dst[2] = v.z; dst[3] = v.w;
    }
    __syncthreads();

    // ---- banded dots, 2 adjacent l per thread (3 LDS reads / 2 FMA) ----
    // items: t in [0,8) x lp in [0,51)  -> 408
    float s0[2], s1[2];
    int ti[2], l0i[2];
    #pragma unroll
    for (int j = 0; j < 2; ++j) {
        int idx = j * 256 + tid;
        const bool valid = idx < TT * 51;
        if (!valid) idx = 0;
        const int t  = idx / 51;
        const int lp = idx - t * 51;
        ti[j]  = valid ? t : -1;
        l0i[j] = lp * 2;
        const float* pa  = p_s + (t + 50) * PS;
        const float* pb0 = p_s + (t + lp * 2) * PS;        // l0 = 2*lp
        const float* pb1 = pb0 + PS;                       // l1 = l0+1 (may be pad row)
        float a0 = 0.f, a1 = 0.f;
        #pragma unroll 8
        for (int k = 0; k < D_DIM; ++k) {
            const float a = pa[k];
            a0 += a * pb0[k];
            a1 += a * pb1[k];
        }
        s0[j] = a0; s1[j] = a1;
    }
    __syncthreads();   // p_s dead; reuse LDS

    // ---- scatter band to LDS, stage Wfc ----
    float* band_s = smem;              // [TT][101] = 808 floats
    float* wfc_s  = smem + TT * L_DIM; // 12928 floats (total 13736 <= 14061)
    #pragma unroll
    for (int j = 0; j < 2; ++j) {
        if (ti[j] >= 0) {
            const int base = ti[j] * L_DIM + l0i[j];
            band_s[base] = s0[j];
            if (l0i[j] + 1 < L_DIM) band_s[base + 1] = s1[j];
        }
    }
    for (int i = tid; i < O_DIM * L_DIM; i += 256) wfc_s[i] = Wfc[i];
    __syncthreads();

    // ---- FC: thread owns (o, 4 t's); 5 LDS reads / 4 FMA ----
    const int o  = tid & 127;
    const int th = tid >> 7;          // t-half: rows th*4 .. th*4+3
    const float bias = bfc[o];
    float acc[4] = {bias, bias, bias, bias};
    const float* w  = wfc_s + o * L_DIM;
    const float* bd = band_s + (th * 4) * L_DIM;
    for (int l = 0; l < L_DIM; ++l) {
        const float wv = w[l];
        acc[0] += bd[0 * L_DIM + l] * wv;
        acc[1] += bd[1 * L_DIM + l] * wv;
        acc[2] += bd[2 * L_DIM + l] * wv;
        acc[3] += bd[3 * L_DIM + l] * wv;
    }
    const size_t obase = (size_t)((b << 10) + t0 + th * 4) * O_DIM + o;
    #pragma unroll
    for (int r = 0; r < 4; ++r)
        out[obase + (size_t)r * O_DIM] = fmaxf(acc[r], 0.f);
}

extern "C" void kernel_launch(void* const* d_in, const int* in_sizes, int n_in,
                              void* d_out, int out_size, void* d_ws, size_t ws_size,
                              hipStream_t stream) {
    const float* x   = (const float*)d_in[0];
    const float* Wp  = (const float*)d_in[1];
    const float* Wfc = (const float*)d_in[2];
    const float* bfc = (const float*)d_in[3];
    float* out = (float*)d_out;

    char* ws = (char*)d_ws;
    float* WpT = (float*)(ws);                            // 256 KB
    float* p   = (float*)(ws + (size_t)1024 * 1024);      // 2 MB

    wpt_kernel<<<(C_DIM * D_DIM) / 256, 256, 0, stream>>>(Wp, WpT);
    pool_proj_kernel<<<(B_DIM * T_DIM) / ROWS, 256, 0, stream>>>(x, WpT, p);
    band_fc_kernel<<<B_DIM * (T_DIM / TT), 256, 0, stream>>>(p, Wfc, bfc, out);
}

// Round 3
// 709.866 us; speedup vs baseline: 1.0546x; 1.0084x over previous
//
#include <hip/hip_runtime.h>
#include <cstdint>
#include <cstddef>

#define B_DIM 4
#define C_DIM 512
#define T_DIM 1024
#define D_DIM 128
#define L_DIM 101
#define O_DIM 128

// ---------------- K0: transpose W_proj (128x512) -> WpT (512x128) ----------------
__global__ __launch_bounds__(256) void wpt_kernel(const float* __restrict__ Wp,
                                                  float* __restrict__ WpT) {
    const int idx = blockIdx.x * 256 + threadIdx.x;   // 65536 total
    const int c = idx >> 7;
    const int d = idx & 127;
    WpT[idx] = Wp[d * C_DIM + c];   // write coalesced, read scattered (L2)
}

// ---------------- K1: fused pool + proj + L2-normalize ----------------
// 4 (b,t) rows per block; 1024 blocks. Memory-bound: streams 512 KB of x per block.
#define ROWS 4
__global__ __launch_bounds__(256) void pool_proj_kernel(const float* __restrict__ x,
                                                        const float* __restrict__ WpT,
                                                        float* __restrict__ p) {
    __shared__ float feat_s[ROWS * C_DIM];          // 8 KB  [row][c]
    __shared__ float red_s[8 * ROWS * D_DIM];       // 16 KB [strm][row][d]
    __shared__ float nrm_s[ROWS * 2];
    const int tid = threadIdx.x;
    const int bt0 = blockIdx.x * ROWS;
    const int b   = bt0 >> 10;
    const int t0  = bt0 & (T_DIM - 1);

    // ---- phase A: spatial mean pool into feat_s ----
    {
        const int sub = tid & 15;   // float4 slot within the 64-float group
        const int grp = tid >> 4;   // 0..15
        #pragma unroll 4
        for (int it = 0; it < (ROWS * C_DIM) / 16; ++it) {   // 128 iters
            const int idx = it * 16 + grp;                    // row*512 + c
            const int row = idx >> 9;
            const int c   = idx & (C_DIM - 1);
            const size_t gidx =
                ((((size_t)b * C_DIM + c) * T_DIM + (t0 + row)) << 6) + (sub << 2);
            const float4 v = *(const float4*)(x + gidx);
            float s = v.x + v.y + v.z + v.w;
            s += __shfl_down(s, 8, 16);
            s += __shfl_down(s, 4, 16);
            s += __shfl_down(s, 2, 16);
            s += __shfl_down(s, 1, 16);
            if (sub == 0) feat_s[idx] = s * (1.0f / 64.0f);
        }
    }
    __syncthreads();

    // ---- phase B: proj.  lane owns d-quad, strm owns c = 8k+strm ----
    {
        const int lane4 = (tid & 31) << 2;   // d0
        const int strm  = tid >> 5;          // 0..7
        float a0[4] = {0,0,0,0}, a1[4] = {0,0,0,0}, a2[4] = {0,0,0,0}, a3[4] = {0,0,0,0};
        for (int ci = 0; ci < C_DIM / 8; ++ci) {
            const int c = ci * 8 + strm;
            const float4 w = *(const float4*)(WpT + (size_t)c * D_DIM + lane4);
            const float f0 = feat_s[0 * C_DIM + c];
            const float f1 = feat_s[1 * C_DIM + c];
            const float f2 = feat_s[2 * C_DIM + c];
            const float f3 = feat_s[3 * C_DIM + c];
            a0[0] += f0 * w.x; a0[1] += f0 * w.y; a0[2] += f0 * w.z; a0[3] += f0 * w.w;
            a1[0] += f1 * w.x; a1[1] += f1 * w.y; a1[2] += f1 * w.z; a1[3] += f1 * w.w;
            a2[0] += f2 * w.x; a2[1] += f2 * w.y; a2[2] += f2 * w.z; a2[3] += f2 * w.w;
            a3[0] += f3 * w.x; a3[1] += f3 * w.y; a3[2] += f3 * w.z; a3[3] += f3 * w.w;
        }
        float* rb = red_s + strm * (ROWS * D_DIM) + lane4;
        *(float4*)(rb + 0 * D_DIM) = make_float4(a0[0], a0[1], a0[2], a0[3]);
        *(float4*)(rb + 1 * D_DIM) = make_float4(a1[0], a1[1], a1[2], a1[3]);
        *(float4*)(rb + 2 * D_DIM) = make_float4(a2[0], a2[1], a2[2], a2[3]);
        *(float4*)(rb + 3 * D_DIM) = make_float4(a3[0], a3[1], a3[2], a3[3]);
    }
    __syncthreads();

    // ---- phase C: combine streams + row-norm + store ----
    float pv[2];
    const int lane = tid & 63;
    const int wv   = tid >> 6;
    #pragma unroll
    for (int j = 0; j < 2; ++j) {
        const int idx = j * 256 + tid;       // row*128 + d
        float v = 0.f;
        #pragma unroll
        for (int s = 0; s < 8; ++s) v += red_s[s * (ROWS * D_DIM) + idx];
        pv[j] = v;
        float ss = v * v;
        ss += __shfl_xor(ss, 32, 64);
        ss += __shfl_xor(ss, 16, 64);
        ss += __shfl_xor(ss,  8, 64);
        ss += __shfl_xor(ss,  4, 64);
        ss += __shfl_xor(ss,  2, 64);
        ss += __shfl_xor(ss,  1, 64);
        if (lane == 0) {
            const int row  = (j * 4 + wv) >> 1;
            const int half = wv & 1;
            nrm_s[row * 2 + half] = ss;
        }
    }
    __syncthreads();
    #pragma unroll
    for (int j = 0; j < 2; ++j) {
        const int idx = j * 256 + tid;
        const int row = idx >> 7;
        const int d   = idx & 127;
        const float ss  = nrm_s[row * 2] + nrm_s[row * 2 + 1];
        const float inv = 1.0f / fmaxf(sqrtf(ss), 1e-12f);
        p[(size_t)(bt0 + row) * D_DIM + d] = pv[j] * inv;
    }
}

// ---------------- K2: fused banded similarity + FC + relu ----------------
// 8 t's per block; 512 blocks; 2 blocks/CU.  All-LDS, b128 everywhere.
#define TT 8
#define PS 132      // p_s row stride: 16B-aligned rows; lane-stride-1 rows -> bank offset 4 (conflict-free b128)
#define NR 109      // rows t0-50 .. t0+58
#define FS 108      // fc stride: 108 mod 32 = 12 -> consecutive-o b128 conflict-free; rows 16B-aligned
#define SMEM_F (TT * FS + O_DIM * FS)   // 14688 floats = 58752 B  (>= NR*PS = 14388)

__global__ __launch_bounds__(256) void band_fc_kernel(const float* __restrict__ p,
                                                      const float* __restrict__ Wfc,
                                                      const float* __restrict__ bfc,
                                                      float* __restrict__ out) {
    __shared__ float smem[SMEM_F];
    float* p_s = smem;                                  // [NR][PS]
    const int tid = threadIdx.x;
    const int b   = blockIdx.x >> 7;
    const int t0  = (blockIdx.x & 127) * TT;

    // ---- load p rows t0-50 .. t0+58 (zero-filled OOB), b128 stores ----
    for (int idx = tid; idx < NR * (D_DIM / 4); idx += 256) {
        const int i  = idx >> 5;
        const int k4 = (idx & 31) << 2;
        const int r  = t0 - 50 + i;
        float4 v = make_float4(0.f, 0.f, 0.f, 0.f);
        if (r >= 0 && r < T_DIM)
            v = *(const float4*)(p + (size_t)((b << 10) + r) * D_DIM + k4);
        *(float4*)(p_s + i * PS + k4) = v;
    }
    __syncthreads();

    // ---- banded dots: thread owns 2(t) x 2(l) with l-split {lq, lq+51} ----
    // dot(t,l) = row(t+50) . row(t+l).  204 active threads, 6 b128 reads / 16 FMA.
    float c00 = 0.f, c01 = 0.f, c10 = 0.f, c11 = 0.f;
    const bool active = tid < 4 * 51;
    const int tp = active ? (tid / 51) : 0;
    const int lq = active ? (tid - tp * 51) : 0;
    {
        const float* pa0  = p_s + (2 * tp + 50) * PS;       // a-row t=2tp
        const float* pa1  = pa0 + PS;                        // a-row t=2tp+1
        const float* pb00 = p_s + (2 * tp + lq) * PS;        // b-row for (dt=0, l=lq)
        const float* pb01 = pb00 + PS;                       // (dt=1, l=lq)
        const float* pb10 = p_s + (2 * tp + lq + 51) * PS;   // (dt=0, l=lq+51)
        const float* pb11 = pb10 + PS;                       // (dt=1, l=lq+51), max row 108
        #pragma unroll 4
        for (int k = 0; k < D_DIM; k += 4) {
            const float4 a0 = *(const float4*)(pa0 + k);
            const float4 a1 = *(const float4*)(pa1 + k);
            const float4 b0 = *(const float4*)(pb00 + k);
            const float4 b1 = *(const float4*)(pb01 + k);
            const float4 b2 = *(const float4*)(pb10 + k);
            const float4 b3 = *(const float4*)(pb11 + k);
            c00 += a0.x * b0.x + a0.y * b0.y + a0.z * b0.z + a0.w * b0.w;
            c01 += a1.x * b1.x + a1.y * b1.y + a1.z * b1.z + a1.w * b1.w;
            c10 += a0.x * b2.x + a0.y * b2.y + a0.z * b2.z + a0.w * b2.w;
            c11 += a1.x * b3.x + a1.y * b3.y + a1.z * b3.z + a1.w * b3.w;
        }
    }
    __syncthreads();   // p_s dead; reuse LDS

    // ---- scatter band + stage Wfc (padded to FS with zeros) ----
    float* band_s = smem;               // [TT][FS]
    float* wfc_s  = smem + TT * FS;     // [O_DIM][FS]
    if (active) {
        band_s[(2 * tp + 0) * FS + lq] = c00;
        band_s[(2 * tp + 1) * FS + lq] = c01;
        if (lq < 50) {   // l = lq+51 in [51,100]
            band_s[(2 * tp + 0) * FS + lq + 51] = c10;
            band_s[(2 * tp + 1) * FS + lq + 51] = c11;
        }
    }
    for (int i = tid; i < TT * 7; i += 256) {            // zero band pads l=101..107
        const int t = i / 7;
        band_s[t * FS + L_DIM + (i - t * 7)] = 0.f;
    }
    for (int i = tid; i < O_DIM * L_DIM; i += 256) {     // stage Wfc
        const int o = i / L_DIM;
        wfc_s[o * FS + (i - o * L_DIM)] = Wfc[i];
    }
    for (int i = tid; i < O_DIM * 7; i += 256) {         // zero Wfc pads
        const int o = i / 7;
        wfc_s[o * FS + L_DIM + (i - o * 7)] = 0.f;
    }
    __syncthreads();

    // ---- FC: thread owns (o, 4 t's); 5 b128 reads / 16 FMA ----
    const int o  = tid & 127;
    const int th = tid >> 7;            // t-quad: rows th*4 .. th*4+3
    const float bias = bfc[o];
    float acc0 = bias, acc1 = bias, acc2 = bias, acc3 = bias;
    const float* w  = wfc_s + o * FS;
    const float* bd = band_s + (th * 4) * FS;
    #pragma unroll 4
    for (int k = 0; k < 104; k += 4) {
        const float4 wv = *(const float4*)(w + k);
        const float4 b0 = *(const float4*)(bd + 0 * FS + k);
        const float4 b1 = *(const float4*)(bd + 1 * FS + k);
        const float4 b2 = *(const float4*)(bd + 2 * FS + k);
        const float4 b3 = *(const float4*)(bd + 3 * FS + k);
        acc0 += wv.x * b0.x + wv.y * b0.y + wv.z * b0.z + wv.w * b0.w;
        acc1 += wv.x * b1.x + wv.y * b1.y + wv.z * b1.z + wv.w * b1.w;
        acc2 += wv.x * b2.x + wv.y * b2.y + wv.z * b2.z + wv.w * b2.w;
        acc3 += wv.x * b3.x + wv.y * b3.y + wv.z * b3.z + wv.w * b3.w;
    }
    const size_t obase = (size_t)((b << 10) + t0 + th * 4) * O_DIM + o;
    out[obase + 0 * O_DIM] = fmaxf(acc0, 0.f);
    out[obase + 1 * O_DIM] = fmaxf(acc1, 0.f);
    out[obase + 2 * O_DIM] = fmaxf(acc2, 0.f);
    out[obase + 3 * O_DIM] = fmaxf(acc3, 0.f);
}

extern "C" void kernel_launch(void* const* d_in, const int* in_sizes, int n_in,
                              void* d_out, int out_size, void* d_ws, size_t ws_size,
                              hipStream_t stream) {
    const float* x   = (const float*)d_in[0];
    const float* Wp  = (const float*)d_in[1];
    const float* Wfc = (const float*)d_in[2];
    const float* bfc = (const float*)d_in[3];
    float* out = (float*)d_out;

    char* ws = (char*)d_ws;
    float* WpT = (float*)(ws);                            // 256 KB
    float* p   = (float*)(ws + (size_t)1024 * 1024);      // 2 MB

    wpt_kernel<<<(C_DIM * D_DIM) / 256, 256, 0, stream>>>(Wp, WpT);
    pool_proj_kernel<<<(B_DIM * T_DIM) / ROWS, 256, 0, stream>>>(x, WpT, p);
    band_fc_kernel<<<B_DIM * (T_DIM / TT), 256, 0, stream>>>(p, Wfc, bfc, out);
}